// Round 4
// baseline (884.210 us; speedup 1.0000x reference)
//
#include <hip/hip_runtime.h>

typedef unsigned short u16;
using short8  = __attribute__((ext_vector_type(8))) short;
using floatx4 = __attribute__((ext_vector_type(4))) float;
using half_t  = _Float16;
using half2_t = __attribute__((ext_vector_type(2))) _Float16;

constexpr int B_ = 256, T_ = 256, I_ = 16, H_ = 256, O_ = 11;
constexpr int HYP = 512;
constexpr int N1_ = H_ * I_ + H_ * H_ + 2 * H_;   // 70144
constexpr int N2_ = O_ * H_ + O_;                 // 2827
constexpr int GN  = N1_ + N2_;                    // 72971

// d_out is float32; offsets in float elements
constexpr size_t OUT_ACT  = 0;
constexpr size_t OUT_BLDI = (size_t)B_ * T_ * 3;            // 196608
constexpr size_t OUT_H    = OUT_BLDI + (size_t)B_ * T_ * 8; // 720896
constexpr size_t OUT_P1   = OUT_H + (size_t)B_ * H_;        // 786432
constexpr size_t OUT_P2   = OUT_P1 + (size_t)B_ * N1_;      // 18743296

__device__ inline float bf2f(u16 u) {
    union { unsigned int i; float f; } v; v.i = ((unsigned int)u) << 16; return v.f;
}
__device__ inline u16 f2bf(float f) {
    unsigned int x = __float_as_uint(f);
    unsigned int r = (x + 0x7fffu + ((x >> 16) & 1u)) >> 16;   // RNE, finite inputs
    return (u16)r;
}
__device__ inline float fdot2(half2_t a, half2_t b, float c) {
#if __has_builtin(__builtin_amdgcn_fdot2)
    return __builtin_amdgcn_fdot2(a, b, c, false);
#else
    return c + (float)a.x * (float)b.x + (float)a.y * (float)b.y;
#endif
}

// Per-tensor dtype sniff (wave-uniform); see R2/R3 notes.
__device__ inline bool sniff_f32(const void* p) {
    const u16* w = (const u16*)p;
    const int lane = threadIdx.x & 63;
    u16 u = w[lane * 2];
    unsigned e = (u >> 7) & 0xFF;
    bool inband = (u == 0) || (e >= 77 && e <= 140);
    return __popcll(__ballot(inband)) < 56;
}
__device__ inline float ldr(const void* p, size_t i, bool f32) {
    return f32 ? ((const float*)p)[i] : bf2f(((const u16*)p)[i]);
}

// ---------------- kernel 1: h1 = relu(bld @ W1 + b1) -> bf16 stash in out[0..65536 floats) --
__global__ void h1_kernel(const void* __restrict__ bld, const void* __restrict__ W1,
                          const void* __restrict__ b1, u16* __restrict__ h1) {
    const bool bldf = sniff_f32(bld);
    const bool w1f  = sniff_f32(W1);
    const bool b1f  = sniff_f32(b1);
    const int b = blockIdx.x;
    const int j = threadIdx.x;
    float acc = ldr(b1, j, b1f);
#pragma unroll
    for (int k = 0; k < 8; k++)
        acc += ldr(bld, b * 8 + k, bldf) * ldr(W1, k * HYP + j, w1f);
    h1[b * HYP + j] = f2bf(fmaxf(acc, 0.f));
}

// ---------------- kernel 1b: W2 [512][GN] -> W2T bf16 [GN][512] (in d_ws) ------------------
// 64x64 tiles via LDS; [k][n] layout padded to 66 for conflict-free transposed b16 reads.
__global__ __launch_bounds__(256) void transpose_kernel(const void* __restrict__ W2,
                                                        u16* __restrict__ W2T) {
    const bool w2f = sniff_f32(W2);
    const int n0 = blockIdx.x * 64;
    const int k0 = blockIdx.y * 64;
    const int tid = threadIdx.x;
    const int nvalid = (GN - n0 < 64) ? (GN - n0) : 64;

    __shared__ u16 tile[64][66];

    // load: thread k = tid>>2 (0..63), nq = tid&3 -> 16 consecutive n
    {
        const int k  = tid >> 2;
        const int nq = tid & 3;
        const size_t rowb = (size_t)(k0 + k) * GN;
        u16 vals[16];
#pragma unroll
        for (int i = 0; i < 16; i++) {
            const int nn = nq * 16 + i;
            vals[i] = (nn < nvalid) ? f2bf(ldr(W2, rowb + n0 + nn, w2f)) : (u16)0;
        }
        unsigned int* dst = (unsigned int*)&tile[k][nq * 16];
#pragma unroll
        for (int i2 = 0; i2 < 8; i2++)
            dst[i2] = (unsigned int)vals[2 * i2] | ((unsigned int)vals[2 * i2 + 1] << 16);
    }
    __syncthreads();

    // store: thread n = tid&63, kq = tid>>6 -> 16 consecutive k, b128x2 to W2T row n
    {
        const int n  = tid & 63;
        const int kq = tid >> 6;
        if (n < nvalid) {
            short8 o0, o1;
#pragma unroll
            for (int j = 0; j < 8; j++) {
                o0[j] = (short)tile[kq * 16 + j][n];
                o1[j] = (short)tile[kq * 16 + 8 + j][n];
            }
            u16* dst = W2T + (size_t)(n0 + n) * 512 + k0 + kq * 16;
            *(short8*)dst = o0;
            *(short8*)(dst + 8) = o1;
        }
    }
}

// ---------------- kernel 2: flat = h1 @ W2T + b2 -> params (f32, d_out), vector B loads ----
__global__ __launch_bounds__(256) void gemmT_kernel(const u16* __restrict__ A,
                                                    const u16* __restrict__ W2T,
                                                    const void* __restrict__ b2,
                                                    float* __restrict__ out) {
    const bool b2f = sniff_f32(b2);
    const int nb   = blockIdx.x * 64;
    const int lane = threadIdx.x & 63;
    const int wid  = threadIdx.x >> 6;
    const int l15  = lane & 15;
    const int q    = lane >> 4;

    int  col[4]; bool cv[4];
#pragma unroll
    for (int j = 0; j < 4; j++) {
        int c = nb + j * 16 + l15;
        cv[j]  = (c < GN);
        col[j] = cv[j] ? c : (GN - 1);
    }

    const u16* ap[4];
#pragma unroll
    for (int i = 0; i < 4; i++)
        ap[i] = A + (wid * 64 + i * 16 + l15) * HYP + q * 8;
    const u16* bp[4];
#pragma unroll
    for (int j = 0; j < 4; j++)
        bp[j] = W2T + (size_t)col[j] * 512 + q * 8;

    floatx4 acc[4][4] = {};

#pragma unroll 4
    for (int ks = 0; ks < 16; ks++) {
        short8 af[4], bfr[4];
#pragma unroll
        for (int i = 0; i < 4; i++)
            af[i] = *(const short8*)(ap[i] + ks * 32);
#pragma unroll
        for (int j = 0; j < 4; j++)
            bfr[j] = *(const short8*)(bp[j] + ks * 32);
#pragma unroll
        for (int i = 0; i < 4; i++)
#pragma unroll
            for (int j = 0; j < 4; j++)
                acc[i][j] = __builtin_amdgcn_mfma_f32_16x16x32_bf16(af[i], bfr[j], acc[i][j], 0, 0, 0);
    }

    const bool isP2 = (nb >= N1_);   // N1_ multiple of 64 -> no straddle
#pragma unroll
    for (int j = 0; j < 4; j++) {
        const float bias = ldr(b2, col[j], b2f);
#pragma unroll
        for (int i = 0; i < 4; i++) {
            const int mbase = wid * 64 + i * 16 + q * 4;
#pragma unroll
            for (int r = 0; r < 4; r++) {
                if (cv[j]) {
                    const float v = acc[i][j][r] + bias;
                    const int m = mbase + r;
                    size_t dst;
                    if (isP2) dst = OUT_P2 + (size_t)m * N2_ + (size_t)(col[j] - N1_);
                    else      dst = OUT_P1 + (size_t)m * N1_ + (size_t)col[j];
                    out[dst] = v;
                }
            }
        }
    }
}

// ---------------- kernel 2-fallback: R3 gemm (scalar strided B loads) ----------------------
template<bool W2F32>
__device__ void gemm_body(const u16* __restrict__ A, const void* __restrict__ Bm,
                          const void* __restrict__ b2, bool b2f,
                          float* __restrict__ out) {
    const int nb   = blockIdx.x * 64;
    const int lane = threadIdx.x & 63;
    const int wid  = threadIdx.x >> 6;
    const int l15  = lane & 15;
    const int q    = lane >> 4;

    int  col[4]; bool cv[4];
#pragma unroll
    for (int j = 0; j < 4; j++) {
        int c = nb + j * 16 + l15;
        cv[j]  = (c < GN);
        col[j] = cv[j] ? c : (GN - 1);
    }
    const u16* ap[4];
#pragma unroll
    for (int i = 0; i < 4; i++)
        ap[i] = A + (wid * 64 + i * 16 + l15) * HYP + q * 8;

    floatx4 acc[4][4] = {};
#pragma unroll 4
    for (int ks = 0; ks < 16; ks++) {
        short8 af[4];
#pragma unroll
        for (int i = 0; i < 4; i++)
            af[i] = *(const short8*)(ap[i] + ks * 32);
        short8 bfr[4];
        const size_t rb = (size_t)(ks * 32 + q * 8) * (size_t)GN;
#pragma unroll
        for (int t = 0; t < 8; t++) {
            const size_t ro = rb + (size_t)t * (size_t)GN;
#pragma unroll
            for (int j = 0; j < 4; j++) {
                if constexpr (W2F32)
                    bfr[j][t] = (short)f2bf(((const float*)Bm)[ro + (size_t)col[j]]);
                else
                    bfr[j][t] = (short)((const u16*)Bm)[ro + (size_t)col[j]];
            }
        }
#pragma unroll
        for (int i = 0; i < 4; i++)
#pragma unroll
            for (int j = 0; j < 4; j++)
                acc[i][j] = __builtin_amdgcn_mfma_f32_16x16x32_bf16(af[i], bfr[j], acc[i][j], 0, 0, 0);
    }
    const bool isP2 = (nb >= N1_);
#pragma unroll
    for (int j = 0; j < 4; j++) {
        const float bias = ldr(b2, col[j], b2f);
#pragma unroll
        for (int i = 0; i < 4; i++) {
            const int mbase = wid * 64 + i * 16 + q * 4;
#pragma unroll
            for (int r = 0; r < 4; r++) {
                if (cv[j]) {
                    const float v = acc[i][j][r] + bias;
                    const int m = mbase + r;
                    size_t dst;
                    if (isP2) dst = OUT_P2 + (size_t)m * N2_ + (size_t)(col[j] - N1_);
                    else      dst = OUT_P1 + (size_t)m * N1_ + (size_t)col[j];
                    out[dst] = v;
                }
            }
        }
    }
}
__global__ __launch_bounds__(256) void gemm_kernel(const u16* A, const void* Bm,
                                                   const void* b2, float* out) {
    const bool w2f = sniff_f32(Bm);
    const bool b2f = sniff_f32(b2);
    if (w2f) gemm_body<true>(A, Bm, b2, b2f, out);
    else     gemm_body<false>(A, Bm, b2, b2f, out);
}

// ---------------- kernel 3: RNN scan v2 — 2 batches/block, full row/thread, 1 barrier/step -
// 128 blocks x 512 thr. Group gg = tid>>8 handles batch 2*blockIdx+gg; g = tid&255 owns row g.
__global__ __launch_bounds__(512) void rnn_kernel(const void* __restrict__ stim,
                                                  float* __restrict__ out) {
    const bool stf = sniff_f32(stim);
    const int tid = threadIdx.x;
    const int gg  = tid >> 8;
    const int g   = tid & 255;
    const int bb  = blockIdx.x * 2 + gg;

    const float* p1 = out + OUT_P1 + (size_t)bb * N1_;
    const float* p2 = out + OUT_P2 + (size_t)bb * N2_;

    __shared__ half2_t hbuf[2][2][128];    // [group][cur/nxt][h as 256 halfs]
    __shared__ half2_t stim_s[2][T_ * 8];  // [group][t*8 + i2]

    // stage stimulus -> half2
    if (stf) {
        const float2* sp = (const float2*)stim + (size_t)bb * T_ * 8;
        for (int idx = g; idx < T_ * 8; idx += 256) {
            float2 v = sp[idx];
            half2_t h; h.x = (half_t)v.x; h.y = (half_t)v.y;
            stim_s[gg][idx] = h;
        }
    } else {
        const unsigned int* sp = (const unsigned int*)((const u16*)stim + (size_t)bb * T_ * I_);
        for (int idx = g; idx < T_ * 8; idx += 256) {
            unsigned int u = sp[idx];
            union { unsigned int i; float f; } lo, hi;
            lo.i = u << 16; hi.i = u & 0xffff0000u;
            half2_t h; h.x = (half_t)lo.f; h.y = (half_t)hi.f;
            stim_s[gg][idx] = h;
        }
    }

    // full W_hh row g -> 128 half2 registers
    half2_t Wr[128];
    {
        const float4* wp4 = (const float4*)(p1 + H_ * I_ + (size_t)g * H_);
#pragma unroll
        for (int v = 0; v < 64; v++) {
            float4 r4 = wp4[v];
            half2_t h01, h23;
            h01.x = (half_t)r4.x; h01.y = (half_t)r4.y;
            h23.x = (half_t)r4.z; h23.y = (half_t)r4.w;
            Wr[v * 2 + 0] = h01;
            Wr[v * 2 + 1] = h23;
        }
    }

    // W_ih row g + combined bias
    half2_t Wih[8];
    float bc;
    {
        const float4* ip = (const float4*)(p1 + (size_t)g * I_);
#pragma unroll
        for (int v = 0; v < 4; v++) {
            float4 r4 = ip[v];
            half2_t h01, h23;
            h01.x = (half_t)r4.x; h01.y = (half_t)r4.y;
            h23.x = (half_t)r4.z; h23.y = (half_t)r4.w;
            Wih[v * 2 + 0] = h01;
            Wih[v * 2 + 1] = h23;
        }
        bc = p1[H_ * I_ + H_ * H_ + g] + p1[H_ * I_ + H_ * H_ + H_ + g];
    }

    // W_out chunk for proj threads (g<176): oo = g>>4, cc = g&15
    half2_t Wo[8];
    float bo = 0.f;
    const int oo = g >> 4, cc = g & 15;
    if (g < 176) {
        const float* wop = p2 + oo * H_ + cc * 16;
#pragma unroll
        for (int v = 0; v < 8; v++) {
            half2_t w;
            w.x = (half_t)wop[2 * v];
            w.y = (half_t)wop[2 * v + 1];
            Wo[v] = w;
        }
        bo = p2[O_ * H_ + oo];
    }

    // h0 = 0
    if (g < 128) {
        half2_t z; z.x = (half_t)0.f; z.y = (half_t)0.f;
        hbuf[gg][0][g] = z;
    }
    __syncthreads();

    const size_t act_base  = OUT_ACT  + (size_t)bb * T_ * 3;
    const size_t bldi_base = OUT_BLDI + (size_t)bb * T_ * 8;

    for (int t = 0; t < T_; t++) {
        const int cur = t & 1, nxt = cur ^ 1;
        const half2_t* hv = hbuf[gg][cur];   // h_{t-1}

        // off-critical-path: project h_{t-1} (valid for t>=1)
        if (g < 176 && t > 0) {
            const half2_t* h2v = &hv[cc * 8];
            float oa = 0.f;
#pragma unroll
            for (int v = 0; v < 8; v++) oa = fdot2(Wo[v], h2v[v], oa);
            oa += __shfl_xor(oa, 1);
            oa += __shfl_xor(oa, 2);
            oa += __shfl_xor(oa, 4);
            oa += __shfl_xor(oa, 8);
            if (cc == 0) {
                float v2 = oa + bo;
                const int tp = t - 1;
                if (oo < 3) {
                    v2 = 1.f / (1.f + __expf(-v2));
                    out[act_base + (size_t)tp * 3 + oo] = v2;
                } else {
                    out[bldi_base + (size_t)tp * 8 + (oo - 3)] = v2;
                }
            }
        }

        // full-row matvec: s = bc + Wih.x_{t-1} + Wr.h_{t-1}
        float a0 = bc, a1 = 0.f, a2 = 0.f, a3 = 0.f;
        if (t > 0) {
            const half2_t* sv = &stim_s[gg][(t - 1) * 8];
#pragma unroll
            for (int i2 = 0; i2 < 8; i2 += 4) {
                a0 = fdot2(Wih[i2 + 0], sv[i2 + 0], a0);
                a1 = fdot2(Wih[i2 + 1], sv[i2 + 1], a1);
                a2 = fdot2(Wih[i2 + 2], sv[i2 + 2], a2);
                a3 = fdot2(Wih[i2 + 3], sv[i2 + 3], a3);
            }
        }
#pragma unroll
        for (int jj = 0; jj < 128; jj += 4) {
            a0 = fdot2(Wr[jj + 0], hv[jj + 0], a0);
            a1 = fdot2(Wr[jj + 1], hv[jj + 1], a1);
            a2 = fdot2(Wr[jj + 2], hv[jj + 2], a2);
            a3 = fdot2(Wr[jj + 3], hv[jj + 3], a3);
        }
        const float s = (a0 + a1) + (a2 + a3);
        const float e = __expf(2.f * s);
        const float hn = 1.f - 2.f / (e + 1.f);   // tanh(s)
        ((half_t*)hbuf[gg][nxt])[g] = (half_t)hn;
        if (t == T_ - 1) out[OUT_H + (size_t)bb * H_ + g] = hn;

        __syncthreads();
    }

    // final projection for h_255 (sits in buffer 0 after 256 iterations)
    if (g < 176) {
        const half2_t* h2v = &hbuf[gg][0][cc * 8];
        float oa = 0.f;
#pragma unroll
        for (int v = 0; v < 8; v++) oa = fdot2(Wo[v], h2v[v], oa);
        oa += __shfl_xor(oa, 1);
        oa += __shfl_xor(oa, 2);
        oa += __shfl_xor(oa, 4);
        oa += __shfl_xor(oa, 8);
        if (cc == 0) {
            float v2 = oa + bo;
            if (oo < 3) {
                v2 = 1.f / (1.f + __expf(-v2));
                out[act_base + (size_t)255 * 3 + oo] = v2;
            } else {
                out[bldi_base + (size_t)255 * 8 + (oo - 3)] = v2;
            }
        }
    }
}

extern "C" void kernel_launch(void* const* d_in, const int* in_sizes, int n_in,
                              void* d_out, int out_size, void* d_ws, size_t ws_size,
                              hipStream_t stream) {
    (void)in_sizes; (void)n_in; (void)out_size;
    const void* bld  = d_in[0];
    const void* stim = d_in[1];
    const void* W1   = d_in[2];
    const void* b1   = d_in[3];
    const void* W2   = d_in[4];
    const void* b2   = d_in[5];
    float* out = (float*)d_out;
    u16* h1 = (u16*)out;   // bf16 stash inside act region (rewritten by rnn)

    h1_kernel<<<B_, HYP, 0, stream>>>(bld, W1, b1, h1);

    const size_t w2t_bytes = (size_t)GN * 512 * sizeof(u16);
    if (ws_size >= w2t_bytes) {
        u16* W2T = (u16*)d_ws;
        transpose_kernel<<<dim3((GN + 63) / 64, 8), 256, 0, stream>>>(W2, W2T);
        gemmT_kernel<<<(GN + 63) / 64, 256, 0, stream>>>(h1, W2T, b2, out);
    } else {
        gemm_kernel<<<(GN + 63) / 64, 256, 0, stream>>>(h1, W2, b2, out);
    }

    rnn_kernel<<<B_ / 2, 512, 0, stream>>>(stim, out);
}